// Round 2
// baseline (547.824 us; speedup 1.0000x reference)
//
#include <hip/hip_runtime.h>
#include <hip/hip_bf16.h>

// Problem constants (from reference setup_inputs)
#define B_    2048
#define N_    64
#define E_    512
#define K_    20
#define C_    6      // self classes; neighbor classes = C_+1
#define DSELF 120    // IN*(OBS+PRED) = 6*20
#define DNEI  48     // IN*OBS = 6*8
#define DPRED 72     // IN*PRED = 6*12
#define EPS_  1e-4f

// ---------------------------------------------------------------------------
// Kernel 1: label-conditioned self embedding (all float32)
//   x[b,k,e] = sum_j traj[b,k,j] * W_self[c_b, j, e] + b_self[c_b, e]
//   traj[b,k,:] = concat(obs[b] flat(48), init_trajs[c_b,k] flat(72))
// One block per b. traj stored transposed [j][k] in LDS so K is contiguous
// -> float4 broadcast reads. Each thread owns e-pair (2*tid, 2*tid+1), holds
// acc[20][2] in registers; W row float2 loads are coalesced and L2-hot
// (W_self total = 1.47 MB f32).
// ---------------------------------------------------------------------------
__global__ __launch_bounds__(256) void self_embed(
    const float* __restrict__ obs,         // [B,48]
    const float* __restrict__ init_trajs,  // [C,K,72]
    const float* __restrict__ W_self,      // [C,120,512]
    const float* __restrict__ b_self,      // [C,512]
    const int*   __restrict__ labels,      // [B]
    float*       __restrict__ out)         // [B,K,512]
{
    const int b   = blockIdx.x;
    const int tid = threadIdx.x;
    const int c   = labels[b];

    __shared__ __align__(16) float traj[DSELF * K_];  // [j][k], 9600 B

    for (int idx = tid; idx < DSELF * K_; idx += 256) {
        const int j = idx / K_;
        const int k = idx - j * K_;
        float v;
        if (j < DNEI) v = obs[b * DNEI + j];
        else          v = init_trajs[(c * K_ + k) * DPRED + (j - DNEI)];
        traj[idx] = v;
    }
    __syncthreads();

    float acc[K_][2];
    #pragma unroll
    for (int k = 0; k < K_; ++k) { acc[k][0] = 0.f; acc[k][1] = 0.f; }

    // float2 view of W_self rows for this class / e-pair (e0 = 2*tid)
    const float2* Wp = reinterpret_cast<const float2*>(W_self + (size_t)c * DSELF * E_) + tid;

    for (int j = 0; j < DSELF; ++j) {
        const float2 w  = Wp[j * (E_ / 2)];
        const float4* tp = reinterpret_cast<const float4*>(&traj[j * K_]);
        #pragma unroll
        for (int q = 0; q < 5; ++q) {
            const float4 t4 = tp[q];
            acc[q * 4 + 0][0] += t4.x * w.x; acc[q * 4 + 0][1] += t4.x * w.y;
            acc[q * 4 + 1][0] += t4.y * w.x; acc[q * 4 + 1][1] += t4.y * w.y;
            acc[q * 4 + 2][0] += t4.z * w.x; acc[q * 4 + 2][1] += t4.z * w.y;
            acc[q * 4 + 3][0] += t4.w * w.x; acc[q * 4 + 3][1] += t4.w * w.y;
        }
    }

    const float2 bs = reinterpret_cast<const float2*>(b_self + c * E_)[tid];
    #pragma unroll
    for (int k = 0; k < K_; ++k) {
        float2 o;
        o.x = acc[k][0] + bs.x;
        o.y = acc[k][1] + bs.y;
        reinterpret_cast<float2*>(out + (size_t)(b * K_ + k) * E_)[tid] = o;
    }
}

// ---------------------------------------------------------------------------
// Kernel 2: label-conditioned neighbor embedding (all float32)
//   nt = signed-reciprocal(neis); nei_feats[b,n,e] = nt[b,n,:] @ W_nei[c_bn] + b_nei[c_bn]
// One block per b. nt for all 64 rows staged in LDS once via float4.
// Loop over 7 classes; each thread register-caches its e-pair's W column
// (96 floats, fully unrolled), then sweeps the 64 rows with a block-uniform
// label branch (labels depend only on n -> zero divergence).
// ---------------------------------------------------------------------------
__global__ __launch_bounds__(256) void nei_embed(
    const float* __restrict__ neis,   // [B,64,48]
    const float* __restrict__ W_nei,  // [C+1,48,512]
    const float* __restrict__ b_nei,  // [C+1,512]
    const int*   __restrict__ labels, // [B,64]
    float*       __restrict__ out)    // [B,64,512]
{
    const int b   = blockIdx.x;
    const int tid = threadIdx.x;

    __shared__ __align__(16) float nt[N_ * DNEI];  // [n][j], 12288 B
    __shared__ int lab[N_];

    if (tid < N_) lab[tid] = labels[b * N_ + tid];

    const float4* np4 = reinterpret_cast<const float4*>(neis + (size_t)b * N_ * DNEI); // 768 float4
    float4* nt4 = reinterpret_cast<float4*>(nt);
    #pragma unroll
    for (int i = 0; i < 3; ++i) {
        const int idx = tid + i * 256;
        float4 v = np4[idx];
        float4 o;
        o.x = (v.x >= 0.f) ? 1.f / (v.x + EPS_) : 1.f / (v.x - EPS_);
        o.y = (v.y >= 0.f) ? 1.f / (v.y + EPS_) : 1.f / (v.y - EPS_);
        o.z = (v.z >= 0.f) ? 1.f / (v.z + EPS_) : 1.f / (v.z - EPS_);
        o.w = (v.w >= 0.f) ? 1.f / (v.w + EPS_) : 1.f / (v.w - EPS_);
        nt4[idx] = o;
    }
    __syncthreads();

    float wl[DNEI], wh[DNEI];

    for (int c = 0; c < C_ + 1; ++c) {
        const float2* Wp = reinterpret_cast<const float2*>(W_nei + (size_t)c * DNEI * E_) + tid;
        #pragma unroll
        for (int j = 0; j < DNEI; ++j) {
            const float2 w = Wp[j * (E_ / 2)];
            wl[j] = w.x;
            wh[j] = w.y;
        }
        const float2 bs = reinterpret_cast<const float2*>(b_nei + c * E_)[tid];

        for (int n = 0; n < N_; ++n) {
            if (lab[n] != c) continue;   // block-uniform branch
            float a0 = bs.x, a1 = bs.y;
            const float4* tp = reinterpret_cast<const float4*>(&nt[n * DNEI]);
            #pragma unroll
            for (int q = 0; q < 12; ++q) {
                const float4 t4 = tp[q];
                a0 += t4.x * wl[q * 4 + 0]; a1 += t4.x * wh[q * 4 + 0];
                a0 += t4.y * wl[q * 4 + 1]; a1 += t4.y * wh[q * 4 + 1];
                a0 += t4.z * wl[q * 4 + 2]; a1 += t4.z * wh[q * 4 + 2];
                a0 += t4.w * wl[q * 4 + 3]; a1 += t4.w * wh[q * 4 + 3];
            }
            float2 o; o.x = a0; o.y = a1;
            reinterpret_cast<float2*>(out + (size_t)(b * N_ + n) * E_)[tid] = o;
        }
    }
}

extern "C" void kernel_launch(void* const* d_in, const int* in_sizes, int n_in,
                              void* d_out, int out_size, void* d_ws, size_t ws_size,
                              hipStream_t stream) {
    const float* obs  = (const float*)d_in[0];
    const float* neis = (const float*)d_in[1];
    const float* it   = (const float*)d_in[2];
    const float* Ws   = (const float*)d_in[3];
    const float* bs   = (const float*)d_in[4];
    const float* Wn   = (const float*)d_in[5];
    const float* bn   = (const float*)d_in[6];
    const int* sl = (const int*)d_in[7];
    const int* nl = (const int*)d_in[8];

    float* out_x = (float*)d_out;                        // [B,K,E]
    float* out_n = out_x + (size_t)B_ * K_ * E_;         // [B,N,E]

    self_embed<<<dim3(B_), dim3(256), 0, stream>>>(obs, it, Ws, bs, sl, out_x);
    nei_embed<<<dim3(B_), dim3(256), 0, stream>>>(neis, Wn, bn, nl, out_n);
}